// Round 24
// baseline (62.363 us; speedup 1.0000x reference)
//
#include <hip/hip_runtime.h>

#define BATCH 16
#define CH    64
#define LEN   4096
#define NCODE 1024
#define NPTS  (BATCH * LEN)   // 65536
#define NPART 512             // argmin blocks
#define UNITB 24576           // staging unit: 2 tiles (one per code-half) = 24KB

typedef float float2v __attribute__((ext_vector_type(2)));
typedef float float4v __attribute__((ext_vector_type(4)));
typedef short short8  __attribute__((ext_vector_type(8)));
typedef float f32x16  __attribute__((ext_vector_type(16)));
typedef unsigned int uint32;

// RNE float->bf16 (bit ops: no dependence on __hip_bfloat16 ABI)
__device__ __forceinline__ unsigned short f2bf(float f) {
    uint32 u = __builtin_bit_cast(uint32, f);
    u += 0x7fffu + ((u >> 16) & 1u);
    return (unsigned short)(u >> 16);
}
__device__ __forceinline__ float bf2f(unsigned short h) {
    uint32 u = ((uint32)h) << 16;
    return __builtin_bit_cast(float, u);
}

// ---------------------------------------------------------------------------
// Kernel 1 (prep): split codebook into bf16x3 MFMA A-fragments + w2 table.
// Step-unit contiguous layout: tile T -> Tp = T<16 ? 2T : 2(T-16)+1
//   cbf2[(Tp*12 + s*3 + sigma)*512 + lane*8 + i]
// 16 blocks x 256 thr, coalesced LDS-tiled staging. 4 threads per code.
// ---------------------------------------------------------------------------
__global__ __launch_bounds__(256) void vq_prep(const float* __restrict__ cb,
                                               short* __restrict__ cbf2,
                                               float* __restrict__ w2tab) {
    __shared__ float tile[64][65];
    __shared__ float s2p[4][64];
    const int k0 = blockIdx.x * 64;
    const int t  = threadIdx.x;
#pragma unroll
    for (int it = 0; it < 4; ++it) {
        int idx = it * 256 + t, row = idx >> 4, q = idx & 15;
        *(float4v*)&tile[row][q * 4] =
            *(const float4v*)&cb[(size_t)(k0 + row) * CH + q * 4];
    }
    __syncthreads();

    const int j  = t & 63;         // code within block
    const int cq = t >> 6;         // channel quarter == k-slice s
    const int k  = k0 + j, T = k >> 5, row = k & 31;
    const int Tp = (T < 16) ? (T * 2) : ((T - 16) * 2 + 1);
    float s2 = 0.f;
#pragma unroll
    for (int cc = 0; cc < 16; ++cc) {
        float xv = tile[j][cq * 16 + cc];
        s2 = fmaf(xv, xv, s2);
        unsigned short h1 = f2bf(xv); float f1 = bf2f(h1);
        float r1 = xv - f1;                     // exact residual
        unsigned short h2 = f2bf(r1); float f2 = bf2f(h2);
        float r2 = r1 - f2;                     // exact residual
        unsigned short h3 = f2bf(r2);
        int g = cc >> 3, i = cc & 7;
        int lane = g * 32 + row;
        size_t base = ((size_t)Tp * 12 + cq * 3) * 512 + lane * 8 + i;
        cbf2[base]        = (short)h1;
        cbf2[base + 512]  = (short)h2;
        cbf2[base + 1024] = (short)h3;
    }
    s2p[cq][j] = s2;
    __syncthreads();
    if (t < 64) {
        float s2t = ((s2p[0][t] + s2p[1][t]) + (s2p[2][t] + s2p[3][t]));
        int kk = k0 + t, TT = kk >> 5, rr = kk & 31;
        int hi = (rr >> 2) & 1, r = (rr & 3) + 4 * (rr >> 3);
        w2tab[((size_t)TT * 2 + hi) * 16 + r] = s2t;
    }
}

// per-tile epilogue: cost = w2 - 2*dot, running argmin (rows ascend in k).
__device__ __forceinline__ void epi(const f32x16& acc, int Tg, int g,
                                    float& bestc, int& bestk,
                                    const float* w2s) {
    const float4v* wt = (const float4v*)(w2s + ((size_t)Tg * 2 + g) * 16);
    float4v w0 = wt[0], w1 = wt[1], w2v = wt[2], w3 = wt[3];
    float wr[16] = {w0.x, w0.y, w0.z, w0.w, w1.x, w1.y, w1.z, w1.w,
                    w2v.x, w2v.y, w2v.z, w2v.w, w3.x, w3.y, w3.z, w3.w};
    int kbase = Tg * 32 + 4 * g;
#pragma unroll
    for (int r = 0; r < 16; ++r) {
        float cost = fmaf(-2.0f, acc[r], wr[r]);
        int kg = kbase + (r & 3) + 8 * (r >> 2);   // ascending in r
        if (cost < bestc) { bestc = cost; bestk = kg; }   // strict <
    }
}

// ---------------------------------------------------------------------------
// Kernel 2: MFMA argmin + fused gather — r18's depth-2 / 3-slot ring engine
// (best measured argmin, 53.9us) with its LDS defect repaired.
// r23 lesson: the 2-slot ring silently cut prefetch depth to 1 (unit loaded
// at step-top is ds_written at step-bottom -> vmcnt stall every step); r18's
// depth-2 (issue tt+2, write tt+1) gives a full step of latency cover.
// r18 defect: 81KB LDS -> 1 block/CU. Fix: merge arrays overlay the ring
// (dead after sweep) -> LDS 73.7KB ring + 4KB w2s = 77.8KB <= 80KB ->
// 2 blocks/CU. __launch_bounds__(512,2): the only RA regime that never
// spilled (r21/r23: 68-88 VGPR clean); est ~75 live <= 128 -> HW grants
// 4 waves/SIMD. + T5 setprio around MFMA cluster.
// Math/k-mapping/tie-breaks byte-identical to r15-r23 passing kernels.
// ---------------------------------------------------------------------------
__global__ void __launch_bounds__(512, 2)
vq_argmin(const float*  __restrict__ x,
          const float*  __restrict__ cb,
          const short*  __restrict__ cbf2,
          const float*  __restrict__ w2tab,
          float*        __restrict__ quant,
          float*        __restrict__ idx_out,
          double*       __restrict__ partial) {
    __shared__ __attribute__((aligned(16))) char  ring[3 * UNITB];  // 72KB
    __shared__ __attribute__((aligned(16))) float w2s[NCODE];       // 4KB

    // merge arrays overlay the ring (used only after the sweep)
    float*  smc  = (float*)ring;                 // [8][32]
    int*    smk  = (int*)(ring + 1024);          // [8][32]
    int*    fidx = (int*)(ring + 2048);          // [128]
    double* sds  = (double*)(ring + 2560);       // [128]

    const int t   = threadIdx.x;
    const int l   = t & 63;
    const int w   = __builtin_amdgcn_readfirstlane(t >> 6);  // 0..7
    const int h2  = w >> 2;                 // code half
    const int ptl = (w & 3) * 32 + (l & 31);
    const int g   = l >> 5;                 // k-half group
    const int p0  = blockIdx.x * 128;
    const int b   = p0 >> 12;
    const int l0  = p0 & (LEN - 1);

    float* xs = (float*)ring;               // x tile overlays ring[0:32KB)

    // ---- stage x tile (coalesced float4) + w2 table into LDS
#pragma unroll
    for (int it = 0; it < 4; ++it) {
        int fi = it * 512 + t, c = fi >> 5, p4 = fi & 31;
        *(float4v*)&xs[c * 128 + 4 * p4] =
            *(const float4v*)&x[((size_t)b * CH + c) * LEN + l0 + 4 * p4];
    }
    w2s[t]       = w2tab[t];
    w2s[t + 512] = w2tab[t + 512];
    __syncthreads();

    // ---- build B-frags (x splits) ONCE + x2 partial over my 32 channels
    short8 B1[4], B2[4], B3[4];
    float x2p = 0.f;
#pragma unroll
    for (int s = 0; s < 4; ++s) {
#pragma unroll
        for (int i = 0; i < 8; ++i) {
            int c = s * 16 + g * 8 + i;     // same k-mapping as A frags
            float xv = xs[c * 128 + ptl];
            x2p = fmaf(xv, xv, x2p);
            unsigned short h1v = f2bf(xv); float f1 = bf2f(h1v);
            float r1 = xv - f1;
            unsigned short h2v = f2bf(r1); float f2 = bf2f(h2v);
            float r2 = r1 - f2;
            unsigned short h3v = f2bf(r2);
            B1[s][i] = (short)h1v; B2[s][i] = (short)h2v; B3[s][i] = (short)h3v;
        }
    }
    const float x2 = x2p + __shfl_xor(x2p, 32, 64);   // lane pairs share point
    __syncthreads();                        // xs dead; ring reuse begins

    const float4v* gsrc = (const float4v*)cbf2;   // 1536 float4 per unit

    // ---- prologue: unit0 -> slot0; unit1 loads in flight
    float4v sA0, sA1, sA2, sB0, sB1, sB2;
    sA0 = gsrc[t]; sA1 = gsrc[512 + t]; sA2 = gsrc[1024 + t];
    {
        float4v* d = (float4v*)ring;
        d[t] = sA0; d[512 + t] = sA1; d[1024 + t] = sA2;
    }
    sA0 = gsrc[1536 + t]; sA1 = gsrc[2048 + t]; sA2 = gsrc[2560 + t];  // unit1
    asm volatile("s_waitcnt lgkmcnt(0)" ::: "memory");
    __builtin_amdgcn_s_barrier();           // slot0 visible; unit1 vmcnt in flight
    asm volatile("" ::: "memory");

    float bestc = 3.4e38f;
    int   bestk = 0;

    // one step: prefetch unit tt+2 into nx, compute tile tt from slot tt%3
    // (single chain, setprio'd), write unit tt+1 (cu, loaded LAST step ->
    // full step of vmcnt cover) to slot (tt+1)%3, lgkm wait + raw barrier.
    auto STEP = [&](int tt, float4v& cu0, float4v& cu1, float4v& cu2,
                    float4v& nx0, float4v& nx1, float4v& nx2) {
        if (tt + 2 < 16) {
            const float4v* gs = gsrc + (size_t)(tt + 2) * 1536;
            nx0 = gs[t]; nx1 = gs[512 + t]; nx2 = gs[1024 + t];
        }
        const short* bp = (const short*)&ring[(tt % 3) * UNITB] + h2 * 6144;
        f32x16 acc = {0.f,0.f,0.f,0.f,0.f,0.f,0.f,0.f,
                      0.f,0.f,0.f,0.f,0.f,0.f,0.f,0.f};
        __builtin_amdgcn_s_setprio(1);      // T5
#pragma unroll
        for (int s = 0; s < 4; ++s) {
            const short* fb = bp + (s * 3) * 512 + l * 8;
            short8 A1 = *(const short8*)(fb);
            short8 A2 = *(const short8*)(fb + 512);
            short8 A3 = *(const short8*)(fb + 1024);
            // 6 split terms: 1, 2^-8, 2^-8, 2^-16, 2^-16, 2^-16
            acc = __builtin_amdgcn_mfma_f32_32x32x16_bf16(A1, B1[s], acc, 0, 0, 0);
            acc = __builtin_amdgcn_mfma_f32_32x32x16_bf16(A1, B2[s], acc, 0, 0, 0);
            acc = __builtin_amdgcn_mfma_f32_32x32x16_bf16(A2, B1[s], acc, 0, 0, 0);
            acc = __builtin_amdgcn_mfma_f32_32x32x16_bf16(A1, B3[s], acc, 0, 0, 0);
            acc = __builtin_amdgcn_mfma_f32_32x32x16_bf16(A3, B1[s], acc, 0, 0, 0);
            acc = __builtin_amdgcn_mfma_f32_32x32x16_bf16(A2, B2[s], acc, 0, 0, 0);
        }
        __builtin_amdgcn_s_setprio(0);
        epi(acc, h2 * 16 + tt, g, bestc, bestk, w2s);
        if (tt + 1 < 16) {
            float4v* d = (float4v*)&ring[((tt + 1) % 3) * UNITB];
            d[t] = cu0; d[512 + t] = cu1; d[1024 + t] = cu2;  // vmcnt: 1 step old
        }
        asm volatile("s_waitcnt lgkmcnt(0)" ::: "memory");
        __builtin_amdgcn_s_barrier();       // raw: vmcnt prefetch stays in flight
        asm volatile("" ::: "memory");
    };

    for (int tp = 0; tp < 8; ++tp) {
        STEP(2 * tp,     sA0, sA1, sA2, sB0, sB1, sB2);
        STEP(2 * tp + 1, sB0, sB1, sB2, sA0, sA1, sA2);
    }

    // ---- merge g-halves within wave (explicit smaller-k tie-break)
    {
        float ob = __shfl_xor(bestc, 32, 64);
        int   ok = __shfl_xor(bestk, 32, 64);
        if (ob < bestc || (ob == bestc && ok < bestk)) { bestc = ob; bestk = ok; }
    }
    __syncthreads();                        // ring sweep done; overlay reuse
    // ---- merge the two code-half waves per point via LDS (overlay on ring)
    if (l < 32) { smc[w * 32 + l] = bestc; smk[w * 32 + l] = bestk; }
    __syncthreads();
    if (w < 4 && l < 32) {
        float ob = smc[(w + 4) * 32 + l];
        int   ok = smk[(w + 4) * 32 + l];
        if (ob < bestc || (ob == bestc && ok < bestk)) { bestc = ob; bestk = ok; }
        idx_out[p0 + w * 32 + l] = (float)bestk;
        fidx[w * 32 + l] = bestk;
        sds[w * 32 + l] = (double)x2 + (double)bestc;   // min d2 = x2 + (w2-2dot)
    }
    __syncthreads();

    // ---- fused gather: quant[b][c][l0+pt] = cb[fidx[pt]][c]
    {
        const int pt = t & 127;
        const int cq = t >> 7;           // 4 channel quarters x 16 ch
        const int k  = fidx[pt];
        const float4v* src = (const float4v*)(cb + (size_t)k * CH + cq * 16);
        float4v v0 = src[0], v1 = src[1], v2 = src[2], v3 = src[3];
        float vr[16] = {v0.x, v0.y, v0.z, v0.w, v1.x, v1.y, v1.z, v1.w,
                        v2.x, v2.y, v2.z, v2.w, v3.x, v3.y, v3.z, v3.w};
#pragma unroll
        for (int j = 0; j < 16; ++j) {
            int c = cq * 16 + j;
            quant[((size_t)b * CH + c) * LEN + l0 + pt] = vr[j];  // coalesced in pt
        }
    }

    if (t == 0) {
        double s = 0.0;
        for (int i = 0; i < 128; ++i) s += sds[i];
        partial[blockIdx.x] = s;
    }
}

// ---------------------------------------------------------------------------
// Kernel 3: final loss reduction over NPART per-block partials.
// ---------------------------------------------------------------------------
__global__ __launch_bounds__(256) void vq_loss(const double* __restrict__ partial,
                                               float*        __restrict__ losses) {
    __shared__ double sred[256];
    double v = 0.0;
#pragma unroll
    for (int i = 0; i < NPART / 256; ++i) v += partial[threadIdx.x + 256 * i];
    sred[threadIdx.x] = v;
    __syncthreads();
    for (int s = 128; s > 0; s >>= 1) {
        if (threadIdx.x < s) sred[threadIdx.x] += sred[threadIdx.x + s];
        __syncthreads();
    }
    if (threadIdx.x == 0) {
        float loss = (float)(sred[0] / (double)((size_t)NPTS * CH));
        losses[0] = loss;   // codebook_loss
        losses[1] = loss;   // commitment_loss (same value)
    }
}

// ---------------------------------------------------------------------------
extern "C" void kernel_launch(void* const* d_in, const int* in_sizes, int n_in,
                              void* d_out, int out_size, void* d_ws, size_t ws_size,
                              hipStream_t stream) {
    const float* x  = (const float*)d_in[0];   // (B, C, L)
    const float* cb = (const float*)d_in[1];   // (K, C)
    float* out = (float*)d_out;

    // d_out: [quant_out (B*C*L)] [codebook_loss] [commitment_loss] [indices (B*L)]
    float* quant_out = out;
    float* losses    = out + (size_t)BATCH * CH * LEN;
    float* idx_out   = losses + 2;

    // ws: [0,4KB) partials(512 dbl); [4KB,8KB) w2tab; [16KB,~400KB) cbf2 splits
    double* partial = (double*)d_ws;
    float*  w2tab   = (float*)((char*)d_ws + 4096);
    short*  cbf2    = (short*)((char*)d_ws + 16384);

    vq_prep<<<16, 256, 0, stream>>>(cb, cbf2, w2tab);
    vq_argmin<<<NPTS / 128, 512, 0, stream>>>(x, cb, cbf2, w2tab,
                                              quant_out, idx_out, partial);
    vq_loss<<<1, 256, 0, stream>>>(partial, losses);
}

// Round 25
// 60.108 us; speedup vs baseline: 1.0375x; 1.0375x over previous
//
#include <hip/hip_runtime.h>

#define BATCH 16
#define CH    64
#define LEN   4096
#define NCODE 1024
#define NPTS  (BATCH * LEN)   // 65536
#define NPART 512             // argmin blocks
#define UNITB 24576           // staging unit: 2 tiles (one per code-half) = 24KB

typedef float float2v __attribute__((ext_vector_type(2)));
typedef float float4v __attribute__((ext_vector_type(4)));
typedef short short8  __attribute__((ext_vector_type(8)));
typedef float f32x16  __attribute__((ext_vector_type(16)));
typedef unsigned int uint32;

// RNE float->bf16 (bit ops: no dependence on __hip_bfloat16 ABI)
__device__ __forceinline__ unsigned short f2bf(float f) {
    uint32 u = __builtin_bit_cast(uint32, f);
    u += 0x7fffu + ((u >> 16) & 1u);
    return (unsigned short)(u >> 16);
}
__device__ __forceinline__ float bf2f(unsigned short h) {
    uint32 u = ((uint32)h) << 16;
    return __builtin_bit_cast(float, u);
}

// ---------------------------------------------------------------------------
// Kernel 1 (prep): split codebook into bf16x3 MFMA A-fragments + w2 table.
// Step-unit contiguous layout: tile T -> Tp = T<16 ? 2T : 2(T-16)+1
//   cbf2[(Tp*12 + s*3 + sigma)*512 + lane*8 + i]
// 16 blocks x 256 thr, coalesced LDS-tiled staging. 4 threads per code.
// ---------------------------------------------------------------------------
__global__ __launch_bounds__(256) void vq_prep(const float* __restrict__ cb,
                                               short* __restrict__ cbf2,
                                               float* __restrict__ w2tab) {
    __shared__ float tile[64][65];
    __shared__ float s2p[4][64];
    const int k0 = blockIdx.x * 64;
    const int t  = threadIdx.x;
#pragma unroll
    for (int it = 0; it < 4; ++it) {
        int idx = it * 256 + t, row = idx >> 4, q = idx & 15;
        *(float4v*)&tile[row][q * 4] =
            *(const float4v*)&cb[(size_t)(k0 + row) * CH + q * 4];
    }
    __syncthreads();

    const int j  = t & 63;         // code within block
    const int cq = t >> 6;         // channel quarter == k-slice s
    const int k  = k0 + j, T = k >> 5, row = k & 31;
    const int Tp = (T < 16) ? (T * 2) : ((T - 16) * 2 + 1);
    float s2 = 0.f;
#pragma unroll
    for (int cc = 0; cc < 16; ++cc) {
        float xv = tile[j][cq * 16 + cc];
        s2 = fmaf(xv, xv, s2);
        unsigned short h1 = f2bf(xv); float f1 = bf2f(h1);
        float r1 = xv - f1;                     // exact residual
        unsigned short h2 = f2bf(r1); float f2 = bf2f(h2);
        float r2 = r1 - f2;                     // exact residual
        unsigned short h3 = f2bf(r2);
        int g = cc >> 3, i = cc & 7;
        int lane = g * 32 + row;
        size_t base = ((size_t)Tp * 12 + cq * 3) * 512 + lane * 8 + i;
        cbf2[base]        = (short)h1;
        cbf2[base + 512]  = (short)h2;
        cbf2[base + 1024] = (short)h3;
    }
    s2p[cq][j] = s2;
    __syncthreads();
    if (t < 64) {
        float s2t = ((s2p[0][t] + s2p[1][t]) + (s2p[2][t] + s2p[3][t]));
        int kk = k0 + t, TT = kk >> 5, rr = kk & 31;
        int hi = (rr >> 2) & 1, r = (rr & 3) + 4 * (rr >> 3);
        w2tab[((size_t)TT * 2 + hi) * 16 + r] = s2t;
    }
}

// per-tile epilogue: cost = w2 - 2*dot, running argmin (rows ascend in k).
__device__ __forceinline__ void epi(const f32x16& acc, int Tg, int g,
                                    float& bestc, int& bestk,
                                    const float* w2s) {
    const float4v* wt = (const float4v*)(w2s + ((size_t)Tg * 2 + g) * 16);
    float4v w0 = wt[0], w1 = wt[1], w2v = wt[2], w3 = wt[3];
    float wr[16] = {w0.x, w0.y, w0.z, w0.w, w1.x, w1.y, w1.z, w1.w,
                    w2v.x, w2v.y, w2v.z, w2v.w, w3.x, w3.y, w3.z, w3.w};
    int kbase = Tg * 32 + 4 * g;
#pragma unroll
    for (int r = 0; r < 16; ++r) {
        float cost = fmaf(-2.0f, acc[r], wr[r]);
        int kg = kbase + (r & 3) + 8 * (r >> 2);   // ascending in r
        if (cost < bestc) { bestc = cost; bestk = kg; }   // strict <
    }
}

// ---------------------------------------------------------------------------
// Kernel 2: MFMA argmin + fused gather — r18's depth-2 / 3-slot ring engine
// restored to its REGISTER REGIME.
// OCCUPANCY MODEL (r16-r24 table): for 512-thr blocks, VGPR<=64 is the
// 2-blocks/CU quantum (occ 32-40%); VGPR 68-88 drops to 1 block (occ 19-20%).
// r18's LDS (81.4KB) fit 2 blocks fine (162.8<=163.8KB) — my r23 "LDS
// defect" diagnosis was wrong; r24's only regression vs r18 was
// launch_bounds(512,2) letting the RA drift 64->72. This round = r24
// byte-identical EXCEPT the attribute reverted to amdgpu_waves_per_eu(4,4),
// which produced the clean 64-reg allocation for this single-chain body in
// r16/r18/r19. Single-variable A/B vs r24.
// ---------------------------------------------------------------------------
__global__ void __launch_bounds__(512)
__attribute__((amdgpu_waves_per_eu(4, 4)))
vq_argmin(const float*  __restrict__ x,
          const float*  __restrict__ cb,
          const short*  __restrict__ cbf2,
          const float*  __restrict__ w2tab,
          float*        __restrict__ quant,
          float*        __restrict__ idx_out,
          double*       __restrict__ partial) {
    __shared__ __attribute__((aligned(16))) char  ring[3 * UNITB];  // 72KB
    __shared__ __attribute__((aligned(16))) float w2s[NCODE];       // 4KB

    // merge arrays overlay the ring (used only after the sweep)
    float*  smc  = (float*)ring;                 // [8][32]
    int*    smk  = (int*)(ring + 1024);          // [8][32]
    int*    fidx = (int*)(ring + 2048);          // [128]
    double* sds  = (double*)(ring + 2560);       // [128]

    const int t   = threadIdx.x;
    const int l   = t & 63;
    const int w   = __builtin_amdgcn_readfirstlane(t >> 6);  // 0..7
    const int h2  = w >> 2;                 // code half
    const int ptl = (w & 3) * 32 + (l & 31);
    const int g   = l >> 5;                 // k-half group
    const int p0  = blockIdx.x * 128;
    const int b   = p0 >> 12;
    const int l0  = p0 & (LEN - 1);

    float* xs = (float*)ring;               // x tile overlays ring[0:32KB)

    // ---- stage x tile (coalesced float4) + w2 table into LDS
#pragma unroll
    for (int it = 0; it < 4; ++it) {
        int fi = it * 512 + t, c = fi >> 5, p4 = fi & 31;
        *(float4v*)&xs[c * 128 + 4 * p4] =
            *(const float4v*)&x[((size_t)b * CH + c) * LEN + l0 + 4 * p4];
    }
    w2s[t]       = w2tab[t];
    w2s[t + 512] = w2tab[t + 512];
    __syncthreads();

    // ---- build B-frags (x splits) ONCE + x2 partial over my 32 channels
    short8 B1[4], B2[4], B3[4];
    float x2p = 0.f;
#pragma unroll
    for (int s = 0; s < 4; ++s) {
#pragma unroll
        for (int i = 0; i < 8; ++i) {
            int c = s * 16 + g * 8 + i;     // same k-mapping as A frags
            float xv = xs[c * 128 + ptl];
            x2p = fmaf(xv, xv, x2p);
            unsigned short h1v = f2bf(xv); float f1 = bf2f(h1v);
            float r1 = xv - f1;
            unsigned short h2v = f2bf(r1); float f2 = bf2f(h2v);
            float r2 = r1 - f2;
            unsigned short h3v = f2bf(r2);
            B1[s][i] = (short)h1v; B2[s][i] = (short)h2v; B3[s][i] = (short)h3v;
        }
    }
    const float x2 = x2p + __shfl_xor(x2p, 32, 64);   // lane pairs share point
    __syncthreads();                        // xs dead; ring reuse begins

    const float4v* gsrc = (const float4v*)cbf2;   // 1536 float4 per unit

    // ---- prologue: unit0 -> slot0; unit1 loads in flight
    float4v sA0, sA1, sA2, sB0, sB1, sB2;
    sA0 = gsrc[t]; sA1 = gsrc[512 + t]; sA2 = gsrc[1024 + t];
    {
        float4v* d = (float4v*)ring;
        d[t] = sA0; d[512 + t] = sA1; d[1024 + t] = sA2;
    }
    sA0 = gsrc[1536 + t]; sA1 = gsrc[2048 + t]; sA2 = gsrc[2560 + t];  // unit1
    asm volatile("s_waitcnt lgkmcnt(0)" ::: "memory");
    __builtin_amdgcn_s_barrier();           // slot0 visible; unit1 vmcnt in flight
    asm volatile("" ::: "memory");

    float bestc = 3.4e38f;
    int   bestk = 0;

    // one step: prefetch unit tt+2 into nx, compute tile tt from slot tt%3
    // (single chain, setprio'd), write unit tt+1 (cu, loaded LAST step ->
    // full step of vmcnt cover) to slot (tt+1)%3, lgkm wait + raw barrier.
    auto STEP = [&](int tt, float4v& cu0, float4v& cu1, float4v& cu2,
                    float4v& nx0, float4v& nx1, float4v& nx2) {
        if (tt + 2 < 16) {
            const float4v* gs = gsrc + (size_t)(tt + 2) * 1536;
            nx0 = gs[t]; nx1 = gs[512 + t]; nx2 = gs[1024 + t];
        }
        const short* bp = (const short*)&ring[(tt % 3) * UNITB] + h2 * 6144;
        f32x16 acc = {0.f,0.f,0.f,0.f,0.f,0.f,0.f,0.f,
                      0.f,0.f,0.f,0.f,0.f,0.f,0.f,0.f};
        __builtin_amdgcn_s_setprio(1);      // T5
#pragma unroll
        for (int s = 0; s < 4; ++s) {
            const short* fb = bp + (s * 3) * 512 + l * 8;
            short8 A1 = *(const short8*)(fb);
            short8 A2 = *(const short8*)(fb + 512);
            short8 A3 = *(const short8*)(fb + 1024);
            // 6 split terms: 1, 2^-8, 2^-8, 2^-16, 2^-16, 2^-16
            acc = __builtin_amdgcn_mfma_f32_32x32x16_bf16(A1, B1[s], acc, 0, 0, 0);
            acc = __builtin_amdgcn_mfma_f32_32x32x16_bf16(A1, B2[s], acc, 0, 0, 0);
            acc = __builtin_amdgcn_mfma_f32_32x32x16_bf16(A2, B1[s], acc, 0, 0, 0);
            acc = __builtin_amdgcn_mfma_f32_32x32x16_bf16(A1, B3[s], acc, 0, 0, 0);
            acc = __builtin_amdgcn_mfma_f32_32x32x16_bf16(A3, B1[s], acc, 0, 0, 0);
            acc = __builtin_amdgcn_mfma_f32_32x32x16_bf16(A2, B2[s], acc, 0, 0, 0);
        }
        __builtin_amdgcn_s_setprio(0);
        epi(acc, h2 * 16 + tt, g, bestc, bestk, w2s);
        if (tt + 1 < 16) {
            float4v* d = (float4v*)&ring[((tt + 1) % 3) * UNITB];
            d[t] = cu0; d[512 + t] = cu1; d[1024 + t] = cu2;  // vmcnt: 1 step old
        }
        asm volatile("s_waitcnt lgkmcnt(0)" ::: "memory");
        __builtin_amdgcn_s_barrier();       // raw: vmcnt prefetch stays in flight
        asm volatile("" ::: "memory");
    };

    for (int tp = 0; tp < 8; ++tp) {
        STEP(2 * tp,     sA0, sA1, sA2, sB0, sB1, sB2);
        STEP(2 * tp + 1, sB0, sB1, sB2, sA0, sA1, sA2);
    }

    // ---- merge g-halves within wave (explicit smaller-k tie-break)
    {
        float ob = __shfl_xor(bestc, 32, 64);
        int   ok = __shfl_xor(bestk, 32, 64);
        if (ob < bestc || (ob == bestc && ok < bestk)) { bestc = ob; bestk = ok; }
    }
    __syncthreads();                        // ring sweep done; overlay reuse
    // ---- merge the two code-half waves per point via LDS (overlay on ring)
    if (l < 32) { smc[w * 32 + l] = bestc; smk[w * 32 + l] = bestk; }
    __syncthreads();
    if (w < 4 && l < 32) {
        float ob = smc[(w + 4) * 32 + l];
        int   ok = smk[(w + 4) * 32 + l];
        if (ob < bestc || (ob == bestc && ok < bestk)) { bestc = ob; bestk = ok; }
        idx_out[p0 + w * 32 + l] = (float)bestk;
        fidx[w * 32 + l] = bestk;
        sds[w * 32 + l] = (double)x2 + (double)bestc;   // min d2 = x2 + (w2-2dot)
    }
    __syncthreads();

    // ---- fused gather: quant[b][c][l0+pt] = cb[fidx[pt]][c]
    {
        const int pt = t & 127;
        const int cq = t >> 7;           // 4 channel quarters x 16 ch
        const int k  = fidx[pt];
        const float4v* src = (const float4v*)(cb + (size_t)k * CH + cq * 16);
        float4v v0 = src[0], v1 = src[1], v2 = src[2], v3 = src[3];
        float vr[16] = {v0.x, v0.y, v0.z, v0.w, v1.x, v1.y, v1.z, v1.w,
                        v2.x, v2.y, v2.z, v2.w, v3.x, v3.y, v3.z, v3.w};
#pragma unroll
        for (int j = 0; j < 16; ++j) {
            int c = cq * 16 + j;
            quant[((size_t)b * CH + c) * LEN + l0 + pt] = vr[j];  // coalesced in pt
        }
    }

    if (t == 0) {
        double s = 0.0;
        for (int i = 0; i < 128; ++i) s += sds[i];
        partial[blockIdx.x] = s;
    }
}

// ---------------------------------------------------------------------------
// Kernel 3: final loss reduction over NPART per-block partials.
// ---------------------------------------------------------------------------
__global__ __launch_bounds__(256) void vq_loss(const double* __restrict__ partial,
                                               float*        __restrict__ losses) {
    __shared__ double sred[256];
    double v = 0.0;
#pragma unroll
    for (int i = 0; i < NPART / 256; ++i) v += partial[threadIdx.x + 256 * i];
    sred[threadIdx.x] = v;
    __syncthreads();
    for (int s = 128; s > 0; s >>= 1) {
        if (threadIdx.x < s) sred[threadIdx.x] += sred[threadIdx.x + s];
        __syncthreads();
    }
    if (threadIdx.x == 0) {
        float loss = (float)(sred[0] / (double)((size_t)NPTS * CH));
        losses[0] = loss;   // codebook_loss
        losses[1] = loss;   // commitment_loss (same value)
    }
}

// ---------------------------------------------------------------------------
extern "C" void kernel_launch(void* const* d_in, const int* in_sizes, int n_in,
                              void* d_out, int out_size, void* d_ws, size_t ws_size,
                              hipStream_t stream) {
    const float* x  = (const float*)d_in[0];   // (B, C, L)
    const float* cb = (const float*)d_in[1];   // (K, C)
    float* out = (float*)d_out;

    // d_out: [quant_out (B*C*L)] [codebook_loss] [commitment_loss] [indices (B*L)]
    float* quant_out = out;
    float* losses    = out + (size_t)BATCH * CH * LEN;
    float* idx_out   = losses + 2;

    // ws: [0,4KB) partials(512 dbl); [4KB,8KB) w2tab; [16KB,~400KB) cbf2 splits
    double* partial = (double*)d_ws;
    float*  w2tab   = (float*)((char*)d_ws + 4096);
    short*  cbf2    = (short*)((char*)d_ws + 16384);

    vq_prep<<<16, 256, 0, stream>>>(cb, cbf2, w2tab);
    vq_argmin<<<NPTS / 128, 512, 0, stream>>>(x, cb, cbf2, w2tab,
                                              quant_out, idx_out, partial);
    vq_loss<<<1, 256, 0, stream>>>(partial, losses);
}

// Round 26
// 59.884 us; speedup vs baseline: 1.0414x; 1.0038x over previous
//
#include <hip/hip_runtime.h>

#define BATCH 16
#define CH    64
#define LEN   4096
#define NCODE 1024
#define NPTS  (BATCH * LEN)   // 65536
#define NPART 512             // argmin blocks
#define UNITB 24576           // staging unit: 2 tiles (one per code-half) = 24KB

typedef float float2v __attribute__((ext_vector_type(2)));
typedef float float4v __attribute__((ext_vector_type(4)));
typedef short short8  __attribute__((ext_vector_type(8)));
typedef float f32x16  __attribute__((ext_vector_type(16)));
typedef unsigned int uint32;

// RNE float->bf16 (bit ops: no dependence on __hip_bfloat16 ABI)
__device__ __forceinline__ unsigned short f2bf(float f) {
    uint32 u = __builtin_bit_cast(uint32, f);
    u += 0x7fffu + ((u >> 16) & 1u);
    return (unsigned short)(u >> 16);
}
__device__ __forceinline__ float bf2f(unsigned short h) {
    uint32 u = ((uint32)h) << 16;
    return __builtin_bit_cast(float, u);
}

// ---------------------------------------------------------------------------
// Kernel 1 (prep): split codebook into bf16x3 MFMA A-fragments + w2 table.
// Step-unit contiguous layout: tile T -> Tp = T<16 ? 2T : 2(T-16)+1
//   cbf2[(Tp*12 + s*3 + sigma)*512 + lane*8 + i]
// 16 blocks x 256 thr, coalesced LDS-tiled staging. 4 threads per code.
// ---------------------------------------------------------------------------
__global__ __launch_bounds__(256) void vq_prep(const float* __restrict__ cb,
                                               short* __restrict__ cbf2,
                                               float* __restrict__ w2tab) {
    __shared__ float tile[64][65];
    __shared__ float s2p[4][64];
    const int k0 = blockIdx.x * 64;
    const int t  = threadIdx.x;
#pragma unroll
    for (int it = 0; it < 4; ++it) {
        int idx = it * 256 + t, row = idx >> 4, q = idx & 15;
        *(float4v*)&tile[row][q * 4] =
            *(const float4v*)&cb[(size_t)(k0 + row) * CH + q * 4];
    }
    __syncthreads();

    const int j  = t & 63;         // code within block
    const int cq = t >> 6;         // channel quarter == k-slice s
    const int k  = k0 + j, T = k >> 5, row = k & 31;
    const int Tp = (T < 16) ? (T * 2) : ((T - 16) * 2 + 1);
    float s2 = 0.f;
#pragma unroll
    for (int cc = 0; cc < 16; ++cc) {
        float xv = tile[j][cq * 16 + cc];
        s2 = fmaf(xv, xv, s2);
        unsigned short h1 = f2bf(xv); float f1 = bf2f(h1);
        float r1 = xv - f1;                     // exact residual
        unsigned short h2 = f2bf(r1); float f2 = bf2f(h2);
        float r2 = r1 - f2;                     // exact residual
        unsigned short h3 = f2bf(r2);
        int g = cc >> 3, i = cc & 7;
        int lane = g * 32 + row;
        size_t base = ((size_t)Tp * 12 + cq * 3) * 512 + lane * 8 + i;
        cbf2[base]        = (short)h1;
        cbf2[base + 512]  = (short)h2;
        cbf2[base + 1024] = (short)h3;
    }
    s2p[cq][j] = s2;
    __syncthreads();
    if (t < 64) {
        float s2t = ((s2p[0][t] + s2p[1][t]) + (s2p[2][t] + s2p[3][t]));
        int kk = k0 + t, TT = kk >> 5, rr = kk & 31;
        int hi = (rr >> 2) & 1, r = (rr & 3) + 4 * (rr >> 3);
        w2tab[((size_t)TT * 2 + hi) * 16 + r] = s2t;
    }
}

// per-tile epilogue: cost = w2 - 2*dot, running argmin (rows ascend in k).
__device__ __forceinline__ void epi(const f32x16& acc, int Tg, int g,
                                    float& bestc, int& bestk,
                                    const float* w2s) {
    const float4v* wt = (const float4v*)(w2s + ((size_t)Tg * 2 + g) * 16);
    float4v w0 = wt[0], w1 = wt[1], w2v = wt[2], w3 = wt[3];
    float wr[16] = {w0.x, w0.y, w0.z, w0.w, w1.x, w1.y, w1.z, w1.w,
                    w2v.x, w2v.y, w2v.z, w2v.w, w3.x, w3.y, w3.z, w3.w};
    int kbase = Tg * 32 + 4 * g;
#pragma unroll
    for (int r = 0; r < 16; ++r) {
        float cost = fmaf(-2.0f, acc[r], wr[r]);
        int kg = kbase + (r & 3) + 8 * (r >> 2);   // ascending in r
        if (cost < bestc) { bestc = cost; bestk = kg; }   // strict <
    }
}

// ---------------------------------------------------------------------------
// Kernel 2: MFMA argmin + fused gather — r25's depth-2 engine on a 2-SLOT ring.
// r25 confirmed the register law (VGPR<=64 <-> multi-block/CU; occ 32.8%,
// argmin 53us, MfmaUtil 41% = bare work floor + latency idle at 4 waves/SIMD).
// Residual cap = LDS: 76KB -> 2 blocks/CU. r23's stall was DEPTH-1 prefetch,
// not the slot count: a 2-slot ring with the depth-2 sA/sB rotation is
// hazard-free (unit tt+1, loaded at step tt-1, written at step tt into slot
// (tt+1)&1 whose readers retired at the step-(tt-1) barrier; every slot
// reuse is separated by lgkmcnt(0)+s_barrier). Ring 3->2 slots: LDS 52KB ->
// 3 blocks/CU = 6 waves/SIMD (VGPR 64 permits 8; wpe only steers the RA).
// Everything else byte-identical to r25.
// ---------------------------------------------------------------------------
__global__ void __launch_bounds__(512)
__attribute__((amdgpu_waves_per_eu(4, 4)))
vq_argmin(const float*  __restrict__ x,
          const float*  __restrict__ cb,
          const short*  __restrict__ cbf2,
          const float*  __restrict__ w2tab,
          float*        __restrict__ quant,
          float*        __restrict__ idx_out,
          double*       __restrict__ partial) {
    __shared__ __attribute__((aligned(16))) char  ring[2 * UNITB];  // 48KB
    __shared__ __attribute__((aligned(16))) float w2s[NCODE];       // 4KB

    // merge arrays overlay the ring (used only after the sweep)
    float*  smc  = (float*)ring;                 // [8][32]
    int*    smk  = (int*)(ring + 1024);          // [8][32]
    int*    fidx = (int*)(ring + 2048);          // [128]
    double* sds  = (double*)(ring + 2560);       // [128]

    const int t   = threadIdx.x;
    const int l   = t & 63;
    const int w   = __builtin_amdgcn_readfirstlane(t >> 6);  // 0..7
    const int h2  = w >> 2;                 // code half
    const int ptl = (w & 3) * 32 + (l & 31);
    const int g   = l >> 5;                 // k-half group
    const int p0  = blockIdx.x * 128;
    const int b   = p0 >> 12;
    const int l0  = p0 & (LEN - 1);

    float* xs = (float*)ring;               // x tile overlays ring[0:32KB)

    // ---- stage x tile (coalesced float4) + w2 table into LDS
#pragma unroll
    for (int it = 0; it < 4; ++it) {
        int fi = it * 512 + t, c = fi >> 5, p4 = fi & 31;
        *(float4v*)&xs[c * 128 + 4 * p4] =
            *(const float4v*)&x[((size_t)b * CH + c) * LEN + l0 + 4 * p4];
    }
    w2s[t]       = w2tab[t];
    w2s[t + 512] = w2tab[t + 512];
    __syncthreads();

    // ---- build B-frags (x splits) ONCE + x2 partial over my 32 channels
    short8 B1[4], B2[4], B3[4];
    float x2p = 0.f;
#pragma unroll
    for (int s = 0; s < 4; ++s) {
#pragma unroll
        for (int i = 0; i < 8; ++i) {
            int c = s * 16 + g * 8 + i;     // same k-mapping as A frags
            float xv = xs[c * 128 + ptl];
            x2p = fmaf(xv, xv, x2p);
            unsigned short h1v = f2bf(xv); float f1 = bf2f(h1v);
            float r1 = xv - f1;
            unsigned short h2v = f2bf(r1); float f2 = bf2f(h2v);
            float r2 = r1 - f2;
            unsigned short h3v = f2bf(r2);
            B1[s][i] = (short)h1v; B2[s][i] = (short)h2v; B3[s][i] = (short)h3v;
        }
    }
    const float x2 = x2p + __shfl_xor(x2p, 32, 64);   // lane pairs share point
    __syncthreads();                        // xs dead; ring reuse begins

    const float4v* gsrc = (const float4v*)cbf2;   // 1536 float4 per unit

    // ---- prologue: unit0 -> slot0; unit1 loads in flight
    float4v sA0, sA1, sA2, sB0, sB1, sB2;
    sA0 = gsrc[t]; sA1 = gsrc[512 + t]; sA2 = gsrc[1024 + t];
    {
        float4v* d = (float4v*)ring;
        d[t] = sA0; d[512 + t] = sA1; d[1024 + t] = sA2;
    }
    sA0 = gsrc[1536 + t]; sA1 = gsrc[2048 + t]; sA2 = gsrc[2560 + t];  // unit1
    asm volatile("s_waitcnt lgkmcnt(0)" ::: "memory");
    __builtin_amdgcn_s_barrier();           // slot0 visible; unit1 vmcnt in flight
    asm volatile("" ::: "memory");

    float bestc = 3.4e38f;
    int   bestk = 0;

    // one step: prefetch unit tt+2 into nx, compute tile tt from slot tt&1
    // (single chain, setprio'd), write unit tt+1 (cu, loaded LAST step ->
    // full step of vmcnt cover) to slot (tt+1)&1, lgkm wait + raw barrier.
    // Slot (tt+1)&1's previous readers (unit tt-1) retired at the step-(tt-1)
    // barrier -> write-after-read safe with one barrier separation.
    auto STEP = [&](int tt, float4v& cu0, float4v& cu1, float4v& cu2,
                    float4v& nx0, float4v& nx1, float4v& nx2) {
        if (tt + 2 < 16) {
            const float4v* gs = gsrc + (size_t)(tt + 2) * 1536;
            nx0 = gs[t]; nx1 = gs[512 + t]; nx2 = gs[1024 + t];
        }
        const short* bp = (const short*)&ring[(tt & 1) * UNITB] + h2 * 6144;
        f32x16 acc = {0.f,0.f,0.f,0.f,0.f,0.f,0.f,0.f,
                      0.f,0.f,0.f,0.f,0.f,0.f,0.f,0.f};
        __builtin_amdgcn_s_setprio(1);      // T5
#pragma unroll
        for (int s = 0; s < 4; ++s) {
            const short* fb = bp + (s * 3) * 512 + l * 8;
            short8 A1 = *(const short8*)(fb);
            short8 A2 = *(const short8*)(fb + 512);
            short8 A3 = *(const short8*)(fb + 1024);
            // 6 split terms: 1, 2^-8, 2^-8, 2^-16, 2^-16, 2^-16
            acc = __builtin_amdgcn_mfma_f32_32x32x16_bf16(A1, B1[s], acc, 0, 0, 0);
            acc = __builtin_amdgcn_mfma_f32_32x32x16_bf16(A1, B2[s], acc, 0, 0, 0);
            acc = __builtin_amdgcn_mfma_f32_32x32x16_bf16(A2, B1[s], acc, 0, 0, 0);
            acc = __builtin_amdgcn_mfma_f32_32x32x16_bf16(A1, B3[s], acc, 0, 0, 0);
            acc = __builtin_amdgcn_mfma_f32_32x32x16_bf16(A3, B1[s], acc, 0, 0, 0);
            acc = __builtin_amdgcn_mfma_f32_32x32x16_bf16(A2, B2[s], acc, 0, 0, 0);
        }
        __builtin_amdgcn_s_setprio(0);
        epi(acc, h2 * 16 + tt, g, bestc, bestk, w2s);
        if (tt + 1 < 16) {
            float4v* d = (float4v*)&ring[((tt + 1) & 1) * UNITB];
            d[t] = cu0; d[512 + t] = cu1; d[1024 + t] = cu2;  // vmcnt: 1 step old
        }
        asm volatile("s_waitcnt lgkmcnt(0)" ::: "memory");
        __builtin_amdgcn_s_barrier();       // raw: vmcnt prefetch stays in flight
        asm volatile("" ::: "memory");
    };

    for (int tp = 0; tp < 8; ++tp) {
        STEP(2 * tp,     sA0, sA1, sA2, sB0, sB1, sB2);
        STEP(2 * tp + 1, sB0, sB1, sB2, sA0, sA1, sA2);
    }

    // ---- merge g-halves within wave (explicit smaller-k tie-break)
    {
        float ob = __shfl_xor(bestc, 32, 64);
        int   ok = __shfl_xor(bestk, 32, 64);
        if (ob < bestc || (ob == bestc && ok < bestk)) { bestc = ob; bestk = ok; }
    }
    __syncthreads();                        // ring sweep done; overlay reuse
    // ---- merge the two code-half waves per point via LDS (overlay on ring)
    if (l < 32) { smc[w * 32 + l] = bestc; smk[w * 32 + l] = bestk; }
    __syncthreads();
    if (w < 4 && l < 32) {
        float ob = smc[(w + 4) * 32 + l];
        int   ok = smk[(w + 4) * 32 + l];
        if (ob < bestc || (ob == bestc && ok < bestk)) { bestc = ob; bestk = ok; }
        idx_out[p0 + w * 32 + l] = (float)bestk;
        fidx[w * 32 + l] = bestk;
        sds[w * 32 + l] = (double)x2 + (double)bestc;   // min d2 = x2 + (w2-2dot)
    }
    __syncthreads();

    // ---- fused gather: quant[b][c][l0+pt] = cb[fidx[pt]][c]
    {
        const int pt = t & 127;
        const int cq = t >> 7;           // 4 channel quarters x 16 ch
        const int k  = fidx[pt];
        const float4v* src = (const float4v*)(cb + (size_t)k * CH + cq * 16);
        float4v v0 = src[0], v1 = src[1], v2 = src[2], v3 = src[3];
        float vr[16] = {v0.x, v0.y, v0.z, v0.w, v1.x, v1.y, v1.z, v1.w,
                        v2.x, v2.y, v2.z, v2.w, v3.x, v3.y, v3.z, v3.w};
#pragma unroll
        for (int j = 0; j < 16; ++j) {
            int c = cq * 16 + j;
            quant[((size_t)b * CH + c) * LEN + l0 + pt] = vr[j];  // coalesced in pt
        }
    }

    if (t == 0) {
        double s = 0.0;
        for (int i = 0; i < 128; ++i) s += sds[i];
        partial[blockIdx.x] = s;
    }
}

// ---------------------------------------------------------------------------
// Kernel 3: final loss reduction over NPART per-block partials.
// ---------------------------------------------------------------------------
__global__ __launch_bounds__(256) void vq_loss(const double* __restrict__ partial,
                                               float*        __restrict__ losses) {
    __shared__ double sred[256];
    double v = 0.0;
#pragma unroll
    for (int i = 0; i < NPART / 256; ++i) v += partial[threadIdx.x + 256 * i];
    sred[threadIdx.x] = v;
    __syncthreads();
    for (int s = 128; s > 0; s >>= 1) {
        if (threadIdx.x < s) sred[threadIdx.x] += sred[threadIdx.x + s];
        __syncthreads();
    }
    if (threadIdx.x == 0) {
        float loss = (float)(sred[0] / (double)((size_t)NPTS * CH));
        losses[0] = loss;   // codebook_loss
        losses[1] = loss;   // commitment_loss (same value)
    }
}

// ---------------------------------------------------------------------------
extern "C" void kernel_launch(void* const* d_in, const int* in_sizes, int n_in,
                              void* d_out, int out_size, void* d_ws, size_t ws_size,
                              hipStream_t stream) {
    const float* x  = (const float*)d_in[0];   // (B, C, L)
    const float* cb = (const float*)d_in[1];   // (K, C)
    float* out = (float*)d_out;

    // d_out: [quant_out (B*C*L)] [codebook_loss] [commitment_loss] [indices (B*L)]
    float* quant_out = out;
    float* losses    = out + (size_t)BATCH * CH * LEN;
    float* idx_out   = losses + 2;

    // ws: [0,4KB) partials(512 dbl); [4KB,8KB) w2tab; [16KB,~400KB) cbf2 splits
    double* partial = (double*)d_ws;
    float*  w2tab   = (float*)((char*)d_ws + 4096);
    short*  cbf2    = (short*)((char*)d_ws + 16384);

    vq_prep<<<16, 256, 0, stream>>>(cb, cbf2, w2tab);
    vq_argmin<<<NPTS / 128, 512, 0, stream>>>(x, cb, cbf2, w2tab,
                                              quant_out, idx_out, partial);
    vq_loss<<<1, 256, 0, stream>>>(partial, losses);
}

// Round 27
// 58.778 us; speedup vs baseline: 1.0610x; 1.0188x over previous
//
#include <hip/hip_runtime.h>

#define BATCH 16
#define CH    64
#define LEN   4096
#define NCODE 1024
#define NPTS  (BATCH * LEN)   // 65536
#define NPART 512             // argmin blocks
#define UNITB 24576           // staging unit: 2 tiles (one per code-half) = 24KB

typedef float float2v __attribute__((ext_vector_type(2)));
typedef float float4v __attribute__((ext_vector_type(4)));
typedef short short8  __attribute__((ext_vector_type(8)));
typedef float f32x16  __attribute__((ext_vector_type(16)));
typedef unsigned int uint32;

// RNE float->bf16 (bit ops: no dependence on __hip_bfloat16 ABI)
__device__ __forceinline__ unsigned short f2bf(float f) {
    uint32 u = __builtin_bit_cast(uint32, f);
    u += 0x7fffu + ((u >> 16) & 1u);
    return (unsigned short)(u >> 16);
}
__device__ __forceinline__ float bf2f(unsigned short h) {
    uint32 u = ((uint32)h) << 16;
    return __builtin_bit_cast(float, u);
}

// async global->LDS DMA, 16B per lane (width-16 variant, m97 pattern).
// LDS dest is wave-uniform base + lane*16; global src is per-lane.
__device__ __forceinline__ void gll16(const void* g, void* l) {
    __builtin_amdgcn_global_load_lds(
        (const __attribute__((address_space(1))) void*)(g),
        (__attribute__((address_space(3))) void*)(l),
        16, 0, 0);
}

// ---------------------------------------------------------------------------
// Kernel 1 (prep): split codebook into bf16x3 MFMA A-fragments + w2 table.
// Step-unit contiguous layout: tile T -> Tp = T<16 ? 2T : 2(T-16)+1
//   cbf2[(Tp*12 + s*3 + sigma)*512 + lane*8 + i]
// 16 blocks x 256 thr, coalesced LDS-tiled staging. 4 threads per code.
// ---------------------------------------------------------------------------
__global__ __launch_bounds__(256) void vq_prep(const float* __restrict__ cb,
                                               short* __restrict__ cbf2,
                                               float* __restrict__ w2tab) {
    __shared__ float tile[64][65];
    __shared__ float s2p[4][64];
    const int k0 = blockIdx.x * 64;
    const int t  = threadIdx.x;
#pragma unroll
    for (int it = 0; it < 4; ++it) {
        int idx = it * 256 + t, row = idx >> 4, q = idx & 15;
        *(float4v*)&tile[row][q * 4] =
            *(const float4v*)&cb[(size_t)(k0 + row) * CH + q * 4];
    }
    __syncthreads();

    const int j  = t & 63;         // code within block
    const int cq = t >> 6;         // channel quarter == k-slice s
    const int k  = k0 + j, T = k >> 5, row = k & 31;
    const int Tp = (T < 16) ? (T * 2) : ((T - 16) * 2 + 1);
    float s2 = 0.f;
#pragma unroll
    for (int cc = 0; cc < 16; ++cc) {
        float xv = tile[j][cq * 16 + cc];
        s2 = fmaf(xv, xv, s2);
        unsigned short h1 = f2bf(xv); float f1 = bf2f(h1);
        float r1 = xv - f1;                     // exact residual
        unsigned short h2 = f2bf(r1); float f2 = bf2f(h2);
        float r2 = r1 - f2;                     // exact residual
        unsigned short h3 = f2bf(r2);
        int g = cc >> 3, i = cc & 7;
        int lane = g * 32 + row;
        size_t base = ((size_t)Tp * 12 + cq * 3) * 512 + lane * 8 + i;
        cbf2[base]        = (short)h1;
        cbf2[base + 512]  = (short)h2;
        cbf2[base + 1024] = (short)h3;
    }
    s2p[cq][j] = s2;
    __syncthreads();
    if (t < 64) {
        float s2t = ((s2p[0][t] + s2p[1][t]) + (s2p[2][t] + s2p[3][t]));
        int kk = k0 + t, TT = kk >> 5, rr = kk & 31;
        int hi = (rr >> 2) & 1, r = (rr & 3) + 4 * (rr >> 3);
        w2tab[((size_t)TT * 2 + hi) * 16 + r] = s2t;
    }
}

// per-tile epilogue: cost = w2 - 2*dot, running argmin (rows ascend in k).
__device__ __forceinline__ void epi(const f32x16& acc, int Tg, int g,
                                    float& bestc, int& bestk,
                                    const float* w2s) {
    const float4v* wt = (const float4v*)(w2s + ((size_t)Tg * 2 + g) * 16);
    float4v w0 = wt[0], w1 = wt[1], w2v = wt[2], w3 = wt[3];
    float wr[16] = {w0.x, w0.y, w0.z, w0.w, w1.x, w1.y, w1.z, w1.w,
                    w2v.x, w2v.y, w2v.z, w2v.w, w3.x, w3.y, w3.z, w3.w};
    int kbase = Tg * 32 + 4 * g;
#pragma unroll
    for (int r = 0; r < 16; ++r) {
        float cost = fmaf(-2.0f, acc[r], wr[r]);
        int kg = kbase + (r & 3) + 8 * (r >> 2);   // ascending in r
        if (cost < bestc) { bestc = cost; bestk = kg; }   // strict <
    }
}

// ---------------------------------------------------------------------------
// Kernel 2: MFMA argmin + fused gather — ASYNC-DMA 3-slot ring.
// r26 evidence: duration decoupled from co-residency (1/2/3-block configs all
// ~53us); the per-step sync cost binds: reg-staging ds_write (implicit vmcnt
// wait) + lgkmcnt(0) drain + 16-wave barrier convoy, every step. Fix:
// __builtin_amdgcn_global_load_lds staging (first use this session):
//  - per step, DMA unit tt+2 into slot (tt+2)%3 (3 calls x 8KB; LDS dest =
//    wave-uniform base + lane*16 = our linear layout);
//  - end of step: counted s_waitcnt vmcnt(3) (unit tt+1 landed; unit tt+2
//    STAYS IN FLIGHT across the barrier - the AITER never-drain pattern) +
//    raw s_barrier. No ds_writes, no lgkm drain, ~24 staging VGPRs freed.
// Hazards: slot (tt+2)%3's readers (unit tt-1) retired before the step-(tt-1)
// barrier, DMA issued after it (WAR safe); vmcnt(3) before each barrier makes
// unit tt+1 visible to all waves (RAW safe). Steps 14/15 peeled for literal
// vmcnt immediates. Math/k-mapping/tie-breaks byte-identical to r15-r26.
// ---------------------------------------------------------------------------
__global__ void __launch_bounds__(512)
__attribute__((amdgpu_waves_per_eu(4, 4)))
vq_argmin(const float*  __restrict__ x,
          const float*  __restrict__ cb,
          const short*  __restrict__ cbf2,
          const float*  __restrict__ w2tab,
          float*        __restrict__ quant,
          float*        __restrict__ idx_out,
          double*       __restrict__ partial) {
    __shared__ __attribute__((aligned(16))) char  ring[3 * UNITB];  // 72KB
    __shared__ __attribute__((aligned(16))) float w2s[NCODE];       // 4KB

    // merge arrays overlay the ring (used only after the sweep)
    float*  smc  = (float*)ring;                 // [8][32]
    int*    smk  = (int*)(ring + 1024);          // [8][32]
    int*    fidx = (int*)(ring + 2048);          // [128]
    double* sds  = (double*)(ring + 2560);       // [128]

    const int t   = threadIdx.x;
    const int l   = t & 63;
    const int w   = __builtin_amdgcn_readfirstlane(t >> 6);  // 0..7
    const int h2  = w >> 2;                 // code half
    const int ptl = (w & 3) * 32 + (l & 31);
    const int g   = l >> 5;                 // k-half group
    const int p0  = blockIdx.x * 128;
    const int b   = p0 >> 12;
    const int l0  = p0 & (LEN - 1);

    float* xs = (float*)ring;               // x tile overlays ring[0:32KB)

    // ---- stage x tile (coalesced float4) + w2 table into LDS
#pragma unroll
    for (int it = 0; it < 4; ++it) {
        int fi = it * 512 + t, c = fi >> 5, p4 = fi & 31;
        *(float4v*)&xs[c * 128 + 4 * p4] =
            *(const float4v*)&x[((size_t)b * CH + c) * LEN + l0 + 4 * p4];
    }
    w2s[t]       = w2tab[t];
    w2s[t + 512] = w2tab[t + 512];
    __syncthreads();

    // ---- build B-frags (x splits) ONCE + x2 partial over my 32 channels
    short8 B1[4], B2[4], B3[4];
    float x2p = 0.f;
#pragma unroll
    for (int s = 0; s < 4; ++s) {
#pragma unroll
        for (int i = 0; i < 8; ++i) {
            int c = s * 16 + g * 8 + i;     // same k-mapping as A frags
            float xv = xs[c * 128 + ptl];
            x2p = fmaf(xv, xv, x2p);
            unsigned short h1v = f2bf(xv); float f1 = bf2f(h1v);
            float r1 = xv - f1;
            unsigned short h2v = f2bf(r1); float f2 = bf2f(h2v);
            float r2 = r1 - f2;
            unsigned short h3v = f2bf(r2);
            B1[s][i] = (short)h1v; B2[s][i] = (short)h2v; B3[s][i] = (short)h3v;
        }
    }
    const float x2 = x2p + __shfl_xor(x2p, 32, 64);   // lane pairs share point
    __syncthreads();                        // xs dead; ring reuse begins

    // DMA one 24KB unit into its slot: 3 calls x (8 waves x 1KB)
    auto issue_unit = [&](int u) {
        const char* gu = (const char*)cbf2 + (size_t)u * UNITB + (size_t)(l * 16);
        char*       lu = ring + (u % 3) * UNITB + w * 1024;   // wave-uniform
#pragma unroll
        for (int j = 0; j < 3; ++j)
            gll16(gu + (w * 1024 + j * 8192), lu + j * 8192);
    };

    // ---- compute one tile from its ring slot (single chain, setprio'd)
    float bestc = 3.4e38f;
    int   bestk = 0;
    auto COMPUTE = [&](int tt) {
        const short* bp = (const short*)&ring[(tt % 3) * UNITB] + h2 * 6144;
        f32x16 acc = {0.f,0.f,0.f,0.f,0.f,0.f,0.f,0.f,
                      0.f,0.f,0.f,0.f,0.f,0.f,0.f,0.f};
        __builtin_amdgcn_s_setprio(1);      // T5
#pragma unroll
        for (int s = 0; s < 4; ++s) {
            const short* fb = bp + (s * 3) * 512 + l * 8;
            short8 A1 = *(const short8*)(fb);
            short8 A2 = *(const short8*)(fb + 512);
            short8 A3 = *(const short8*)(fb + 1024);
            // 6 split terms: 1, 2^-8, 2^-8, 2^-16, 2^-16, 2^-16
            acc = __builtin_amdgcn_mfma_f32_32x32x16_bf16(A1, B1[s], acc, 0, 0, 0);
            acc = __builtin_amdgcn_mfma_f32_32x32x16_bf16(A1, B2[s], acc, 0, 0, 0);
            acc = __builtin_amdgcn_mfma_f32_32x32x16_bf16(A2, B1[s], acc, 0, 0, 0);
            acc = __builtin_amdgcn_mfma_f32_32x32x16_bf16(A1, B3[s], acc, 0, 0, 0);
            acc = __builtin_amdgcn_mfma_f32_32x32x16_bf16(A3, B1[s], acc, 0, 0, 0);
            acc = __builtin_amdgcn_mfma_f32_32x32x16_bf16(A2, B2[s], acc, 0, 0, 0);
        }
        __builtin_amdgcn_s_setprio(0);
        epi(acc, h2 * 16 + tt, g, bestc, bestk, w2s);
    };

    // ---- prologue: DMA unit0 + unit1; wait unit0 only (unit1 in flight)
    issue_unit(0);
    issue_unit(1);
    asm volatile("s_waitcnt vmcnt(3)" ::: "memory");
    __builtin_amdgcn_s_barrier();
    asm volatile("" ::: "memory");

    // ---- steps 0..13: issue tt+2, compute tt, counted wait (never drain)
    for (int tt = 0; tt < 14; ++tt) {
        issue_unit(tt + 2);
        COMPUTE(tt);
        asm volatile("s_waitcnt vmcnt(3)" ::: "memory");
        __builtin_amdgcn_s_barrier();
        asm volatile("" ::: "memory");
    }
    // ---- step 14: no issue; drain (unit15 must land)
    COMPUTE(14);
    asm volatile("s_waitcnt vmcnt(0)" ::: "memory");
    __builtin_amdgcn_s_barrier();
    asm volatile("" ::: "memory");
    // ---- step 15: last tile
    COMPUTE(15);

    // ---- merge g-halves within wave (explicit smaller-k tie-break)
    {
        float ob = __shfl_xor(bestc, 32, 64);
        int   ok = __shfl_xor(bestk, 32, 64);
        if (ob < bestc || (ob == bestc && ok < bestk)) { bestc = ob; bestk = ok; }
    }
    __syncthreads();                        // ring sweep done; overlay reuse
    // ---- merge the two code-half waves per point via LDS (overlay on ring)
    if (l < 32) { smc[w * 32 + l] = bestc; smk[w * 32 + l] = bestk; }
    __syncthreads();
    if (w < 4 && l < 32) {
        float ob = smc[(w + 4) * 32 + l];
        int   ok = smk[(w + 4) * 32 + l];
        if (ob < bestc || (ob == bestc && ok < bestk)) { bestc = ob; bestk = ok; }
        idx_out[p0 + w * 32 + l] = (float)bestk;
        fidx[w * 32 + l] = bestk;
        sds[w * 32 + l] = (double)x2 + (double)bestc;   // min d2 = x2 + (w2-2dot)
    }
    __syncthreads();

    // ---- fused gather: quant[b][c][l0+pt] = cb[fidx[pt]][c]
    {
        const int pt = t & 127;
        const int cq = t >> 7;           // 4 channel quarters x 16 ch
        const int k  = fidx[pt];
        const float4v* src = (const float4v*)(cb + (size_t)k * CH + cq * 16);
        float4v v0 = src[0], v1 = src[1], v2 = src[2], v3 = src[3];
        float vr[16] = {v0.x, v0.y, v0.z, v0.w, v1.x, v1.y, v1.z, v1.w,
                        v2.x, v2.y, v2.z, v2.w, v3.x, v3.y, v3.z, v3.w};
#pragma unroll
        for (int j = 0; j < 16; ++j) {
            int c = cq * 16 + j;
            quant[((size_t)b * CH + c) * LEN + l0 + pt] = vr[j];  // coalesced in pt
        }
    }

    if (t == 0) {
        double s = 0.0;
        for (int i = 0; i < 128; ++i) s += sds[i];
        partial[blockIdx.x] = s;
    }
}

// ---------------------------------------------------------------------------
// Kernel 3: final loss reduction over NPART per-block partials.
// ---------------------------------------------------------------------------
__global__ __launch_bounds__(256) void vq_loss(const double* __restrict__ partial,
                                               float*        __restrict__ losses) {
    __shared__ double sred[256];
    double v = 0.0;
#pragma unroll
    for (int i = 0; i < NPART / 256; ++i) v += partial[threadIdx.x + 256 * i];
    sred[threadIdx.x] = v;
    __syncthreads();
    for (int s = 128; s > 0; s >>= 1) {
        if (threadIdx.x < s) sred[threadIdx.x] += sred[threadIdx.x + s];
        __syncthreads();
    }
    if (threadIdx.x == 0) {
        float loss = (float)(sred[0] / (double)((size_t)NPTS * CH));
        losses[0] = loss;   // codebook_loss
        losses[1] = loss;   // commitment_loss (same value)
    }
}

// ---------------------------------------------------------------------------
extern "C" void kernel_launch(void* const* d_in, const int* in_sizes, int n_in,
                              void* d_out, int out_size, void* d_ws, size_t ws_size,
                              hipStream_t stream) {
    const float* x  = (const float*)d_in[0];   // (B, C, L)
    const float* cb = (const float*)d_in[1];   // (K, C)
    float* out = (float*)d_out;

    // d_out: [quant_out (B*C*L)] [codebook_loss] [commitment_loss] [indices (B*L)]
    float* quant_out = out;
    float* losses    = out + (size_t)BATCH * CH * LEN;
    float* idx_out   = losses + 2;

    // ws: [0,4KB) partials(512 dbl); [4KB,8KB) w2tab; [16KB,~400KB) cbf2 splits
    double* partial = (double*)d_ws;
    float*  w2tab   = (float*)((char*)d_ws + 4096);
    short*  cbf2    = (short*)((char*)d_ws + 16384);

    vq_prep<<<16, 256, 0, stream>>>(cb, cbf2, w2tab);
    vq_argmin<<<NPTS / 128, 512, 0, stream>>>(x, cb, cbf2, w2tab,
                                              quant_out, idx_out, partial);
    vq_loss<<<1, 256, 0, stream>>>(partial, losses);
}